// Round 4
// baseline (305.620 us; speedup 1.0000x reference)
//
#include <hip/hip_runtime.h>
#include <math.h>

#define T_DIM 5
#define Z_DIM 32
#define Y_DIM 512
#define X_DIM 512
#define N_RAYS 10000
#define N_STEPS 768
#define VOXEL_F 0.2f
#define NBUCKET 64

// ws layout (floats):
//   [0, 256)                      : 64 loss buckets x {sum|d|, .5d^2, absrel, count}
//   [256, 256 + 8*N_RAYS)         : per-ray records, sorted by tindex, 2 x float4:
//                                   rec[2i]   = {ox,oy,oz, bits(ti<<10 | n_active)}
//                                   rec[2i+1] = {ux,uy,uz, gt_vox}
#define REC_OFF 256

// Single-block: counting-sort rays by tindex (ballot histogram + per-wave rank
// scatter -> ~80 LDS atomics instead of 20000) AND precompute all per-ray
// params so render's dependent-load chain is one 32B broadcast read.
__global__ __launch_bounds__(1024) void prep_kernel(
    const float* __restrict__ origin,   // [T,3] meters
    const float* __restrict__ points,   // [N_RAYS,3] meters
    const int*   __restrict__ tindex,   // [N_RAYS]
    float*       __restrict__ buckets,  // [NBUCKET*4] zeroed here
    float4*      __restrict__ rec)      // [N_RAYS*2]
{
    const int tid  = (int)threadIdx.x;
    const int lane = tid & 63;
    __shared__ int   cnt[T_DIM];
    __shared__ int   base[T_DIM];
    __shared__ float sorg[T_DIM * 3];

    if (tid < NBUCKET * 4) buckets[tid] = 0.0f;
    if (tid < T_DIM) cnt[tid] = 0;
    if (tid < T_DIM * 3) sorg[tid] = origin[tid];
    __syncthreads();

    // Histogram (ballot-based; inactive tail lanes get ti=-1).
    for (int i = tid; i < 10240; i += 1024) {
        const int ti = (i < N_RAYS) ? tindex[i] : -1;
#pragma unroll
        for (int t = 0; t < T_DIM; ++t) {
            const unsigned long long m = __ballot(ti == t);
            if (lane == 0 && m) atomicAdd(&cnt[t], __popcll(m));
        }
    }
    __syncthreads();
    if (tid == 0) {
        int run = 0;
        for (int t = 0; t < T_DIM; ++t) { base[t] = run; run += cnt[t]; }
    }
    __syncthreads();

    // Scatter + precompute ray params.
    for (int i = tid; i < 10240; i += 1024) {
        const int ti = (i < N_RAYS) ? tindex[i] : -1;
        int pos = -1;
#pragma unroll
        for (int t = 0; t < T_DIM; ++t) {
            const unsigned long long m = __ballot(ti == t);
            if (ti == t) {
                const int rank   = __popcll(m & ((1ull << lane) - 1ull));
                const int leader = __ffsll((long long)m) - 1;
                int b = 0;
                if (lane == leader) b = atomicAdd(&base[t], __popcll(m));
                b = __shfl(b, leader, 64);
                pos = b + rank;
            }
        }
        if (ti >= 0) {
            const float ox = (sorg[ti * 3 + 0] + 51.2f) * 5.0f;
            const float oy = (sorg[ti * 3 + 1] + 51.2f) * 5.0f;
            const float oz = (sorg[ti * 3 + 2] + 3.2f) * 5.0f;
            const float px = (points[i * 3 + 0] + 51.2f) * 5.0f;
            const float py = (points[i * 3 + 1] + 51.2f) * 5.0f;
            const float pz = (points[i * 3 + 2] + 3.2f) * 5.0f;
            const float dx = px - ox, dy = py - oy, dz = pz - oz;
            const float gt_vox = sqrtf(dx * dx + dy * dy + dz * dz);
            const float inv = 1.0f / fmaxf(gt_vox, 1e-6f);
            const float ux = dx * inv, uy = dy * inv, uz = dz * inv;

            // Analytic box exit (origin is always inside the volume).
            // IEEE inf handles /0; fmaxf/fminf discard NaN (0/0); per-step
            // inb check in render still guards edge cases exactly.
            float thi = 1e30f;
            thi = fminf(thi, fmaxf((0.0f - ox) / ux, ((float)X_DIM - ox) / ux));
            thi = fminf(thi, fmaxf((0.0f - oy) / uy, ((float)Y_DIM - oy) / uy));
            thi = fminf(thi, fmaxf((0.0f - oz) / uz, ((float)Z_DIM - oz) / uz));
            int n_active = (int)ceilf(fminf(thi, 769.0f) - 0.5f);
            n_active = min(N_STEPS, max(0, n_active));

            float4 r0, r1;
            r0.x = ox; r0.y = oy; r0.z = oz;
            r0.w = __int_as_float((ti << 10) | n_active);
            r1.x = ux; r1.y = uy; r1.z = uz; r1.w = gt_vox;
            rec[2 * pos + 0] = r0;
            rec[2 * pos + 1] = r1;
        }
    }
}

// One wave per sorted ray. Iteration j: lane L handles step 64j+L (64
// consecutive voxels per wave gather). Early-out when transmittance < 1e-7
// (residual weight < 1e-7*768*0.2 m = 1.5e-4 m << 4.28 threshold).
__global__ __launch_bounds__(256) void render_rays_kernel(
    const float*  __restrict__ grid,     // [T,Z,Y,X] raw feats (relu here)
    const float4* __restrict__ rec,      // [N_RAYS*2] sorted records
    float*        __restrict__ buckets)  // [NBUCKET*4]
{
    const int wid  = (int)((blockIdx.x * blockDim.x + threadIdx.x) >> 6);
    const int lane = (int)(threadIdx.x & 63);
    if (wid >= N_RAYS) return;

    const float4 r0 = rec[2 * wid + 0];   // wave-uniform address -> broadcast
    const float4 r1 = rec[2 * wid + 1];
    const float ox = r0.x, oy = r0.y, oz = r0.z;
    const int   pack = __float_as_int(r0.w);
    const int   ti = pack >> 10;
    const int   n_active = pack & 1023;
    const float ux = r1.x, uy = r1.y, uz = r1.z, gt_vox = r1.w;

    const float* gbase = grid + (size_t)ti * (size_t)(Z_DIM * Y_DIM * X_DIM);
    const int iters = (n_active + 63) >> 6;

    float lane_acc = 0.0f;   // this lane's weighted-t contributions
    float ecarry   = 1.0f;   // exp(-sum tau of previous chunks), wave-uniform

    for (int j = 0; j < iters; ++j) {
        const int step = (j << 6) + lane;
        const float tt = (float)step + 0.5f;
        const int ix = (int)floorf(fmaf(ux, tt, ox));
        const int iy = (int)floorf(fmaf(uy, tt, oy));
        const int iz = (int)floorf(fmaf(uz, tt, oz));
        const bool inb = (ix >= 0) & (ix < X_DIM) & (iy >= 0) & (iy < Y_DIM) &
                         (iz >= 0) & (iz < Z_DIM);
        float tau = 0.0f;
        if ((step < n_active) && inb) {
            tau = fmaxf(gbase[((size_t)iz * Y_DIM + (size_t)iy) * X_DIM + (size_t)ix], 0.0f);
        }

        // Inclusive prefix sum of tau across lanes (steps are lane-ordered).
        float scan = tau;
#pragma unroll
        for (int d = 1; d < 64; d <<= 1) {
            const float up = __shfl_up(scan, d, 64);
            if (lane >= d) scan += up;
        }

        // weight = e^{-(scan-tau)} - e^{-scan}; exactly 0 when tau==0.
        const float e_scan = expf(-scan);
        lane_acc += ecarry * (expf(tau - scan) - e_scan) * tt;

        ecarry *= __shfl(e_scan, 63, 64);   // e^{-chunk total}, wave-uniform
        if (ecarry < 1e-7f) break;
    }

#pragma unroll
    for (int d = 32; d >= 1; d >>= 1) lane_acc += __shfl_xor(lane_acc, d, 64);

    if (lane == 0) {
        const float pred_m = lane_acc * VOXEL_F;
        const float gt_m   = gt_vox * VOXEL_F;
        const float diff = gt_m - pred_m;
        const float ad   = fabsf(diff);
        float* b = buckets + 4 * (wid & (NBUCKET - 1));
        atomicAdd(&b[0], ad);
        atomicAdd(&b[1], 0.5f * diff * diff);
        atomicAdd(&b[2], ad / fmaxf(gt_m, 1e-6f));
        atomicAdd(&b[3], 1.0f);
    }
}

__global__ void finalize_kernel(const float* __restrict__ buckets,
                                float* __restrict__ out)
{
    const int lane = (int)(threadIdx.x & 63);
    float4 v = reinterpret_cast<const float4*>(buckets)[lane];
#pragma unroll
    for (int d = 32; d >= 1; d >>= 1) {
        v.x += __shfl_xor(v.x, d, 64);
        v.y += __shfl_xor(v.y, d, 64);
        v.z += __shfl_xor(v.z, d, 64);
        v.w += __shfl_xor(v.w, d, 64);
    }
    if (lane == 0) {
        const float cnt = fmaxf(v.w, 1.0f);
        out[0] = v.x / cnt;
        out[1] = v.y / cnt;
        out[2] = v.z / cnt;
    }
}

extern "C" void kernel_launch(void* const* d_in, const int* in_sizes, int n_in,
                              void* d_out, int out_size, void* d_ws, size_t ws_size,
                              hipStream_t stream) {
    const float* grid    = (const float*)d_in[0];   // (1,5,32,512,512) fp32
    const float* origin  = (const float*)d_in[1];   // (1,5,3) fp32
    const float* points  = (const float*)d_in[2];   // (1,10000,3) fp32
    const int*   tindex  = (const int*)d_in[3];     // (1,10000) int32
    float*  out     = (float*)d_out;
    float*  ws      = (float*)d_ws;
    float*  buckets = ws;
    float4* rec     = (float4*)(ws + REC_OFF);

    prep_kernel<<<1, 1024, 0, stream>>>(origin, points, tindex, buckets, rec);

    const int waves_per_block = 256 / 64;                                 // 4 rays/block
    const int blocks = (N_RAYS + waves_per_block - 1) / waves_per_block;  // 2500
    render_rays_kernel<<<blocks, 256, 0, stream>>>(grid, rec, buckets);

    finalize_kernel<<<1, 64, 0, stream>>>(buckets, out);
}

// Round 5
// 237.751 us; speedup vs baseline: 1.2855x; 1.2855x over previous
//
#include <hip/hip_runtime.h>
#include <math.h>

#define T_DIM 5
#define Z_DIM 32
#define Y_DIM 512
#define X_DIM 512
#define N_RAYS 10000
#define N_STEPS 768
#define VOXEL_F 0.2f

// ws layout (floats):
//   [0, 4*N_RAYS)                 : per-ray float4 {|d|, .5d^2, absrel, 1.0}
//   [4*N_RAYS, 4*N_RAYS+8*N_RAYS) : per-ray records, sorted by tindex, 2 x float4:
//                                   rec[2i]   = {ox,oy,oz, bits(ti<<10 | n_active)}
//                                   rec[2i+1] = {ux,uy,uz, gt_vox}
#define REC_OFF (4 * N_RAYS)

// Single-block: counting-sort rays by tindex (ballot histogram + per-wave rank
// scatter) AND precompute all per-ray params so render's dependent-load chain
// is one 32B wave-uniform read.
__global__ __launch_bounds__(1024) void prep_kernel(
    const float* __restrict__ origin,   // [T,3] meters
    const float* __restrict__ points,   // [N_RAYS,3] meters
    const int*   __restrict__ tindex,   // [N_RAYS]
    float4*      __restrict__ rec)      // [N_RAYS*2]
{
    const int tid  = (int)threadIdx.x;
    const int lane = tid & 63;
    __shared__ int   cnt[T_DIM];
    __shared__ int   base[T_DIM];
    __shared__ float sorg[T_DIM * 3];

    if (tid < T_DIM) cnt[tid] = 0;
    if (tid < T_DIM * 3) sorg[tid] = origin[tid];
    __syncthreads();

    // Histogram (ballot-based; tail lanes get ti=-1).
    for (int i = tid; i < 10240; i += 1024) {
        const int ti = (i < N_RAYS) ? tindex[i] : -1;
#pragma unroll
        for (int t = 0; t < T_DIM; ++t) {
            const unsigned long long m = __ballot(ti == t);
            if (lane == 0 && m) atomicAdd(&cnt[t], __popcll(m));
        }
    }
    __syncthreads();
    if (tid == 0) {
        int run = 0;
        for (int t = 0; t < T_DIM; ++t) { base[t] = run; run += cnt[t]; }
    }
    __syncthreads();

    // Scatter + precompute ray params.
    for (int i = tid; i < 10240; i += 1024) {
        const int ti = (i < N_RAYS) ? tindex[i] : -1;
        int pos = -1;
#pragma unroll
        for (int t = 0; t < T_DIM; ++t) {
            const unsigned long long m = __ballot(ti == t);
            if (ti == t) {
                const int rank   = __popcll(m & ((1ull << lane) - 1ull));
                const int leader = __ffsll((long long)m) - 1;
                int b = 0;
                if (lane == leader) b = atomicAdd(&base[t], __popcll(m));
                b = __shfl(b, leader, 64);
                pos = b + rank;
            }
        }
        if (ti >= 0) {
            const float ox = (sorg[ti * 3 + 0] + 51.2f) * 5.0f;
            const float oy = (sorg[ti * 3 + 1] + 51.2f) * 5.0f;
            const float oz = (sorg[ti * 3 + 2] + 3.2f) * 5.0f;
            const float px = (points[i * 3 + 0] + 51.2f) * 5.0f;
            const float py = (points[i * 3 + 1] + 51.2f) * 5.0f;
            const float pz = (points[i * 3 + 2] + 3.2f) * 5.0f;
            const float dx = px - ox, dy = py - oy, dz = pz - oz;
            const float gt_vox = sqrtf(dx * dx + dy * dy + dz * dz);
            const float inv = 1.0f / fmaxf(gt_vox, 1e-6f);
            const float ux = dx * inv, uy = dy * inv, uz = dz * inv;

            // Analytic box exit (origin is always inside the volume).
            // IEEE inf handles /0; fmaxf/fminf discard NaN (0/0); per-step
            // inb check in render still guards edge cases exactly.
            float thi = 1e30f;
            thi = fminf(thi, fmaxf((0.0f - ox) / ux, ((float)X_DIM - ox) / ux));
            thi = fminf(thi, fmaxf((0.0f - oy) / uy, ((float)Y_DIM - oy) / uy));
            thi = fminf(thi, fmaxf((0.0f - oz) / uz, ((float)Z_DIM - oz) / uz));
            int n_active = (int)ceilf(fminf(thi, 769.0f) - 0.5f);
            n_active = min(N_STEPS, max(0, n_active));

            float4 r0, r1;
            r0.x = ox; r0.y = oy; r0.z = oz;
            r0.w = __int_as_float((ti << 10) | n_active);
            r1.x = ux; r1.y = uy; r1.z = uz; r1.w = gt_vox;
            rec[2 * pos + 0] = r0;
            rec[2 * pos + 1] = r1;
        }
    }
}

// One wave per sorted ray. Iteration j: lane L handles step 64j+L (64
// consecutive voxels per wave gather). Early-out when transmittance < 1e-7
// (residual weight < 1e-7*768*0.2 m = 1.5e-4 m << 4.28 threshold).
// Loss: per-ray non-atomic coalesced float4 store (contended device atomics
// cost ~90 us here -- measured R3 vs R4).
__global__ __launch_bounds__(256) void render_rays_kernel(
    const float*  __restrict__ grid,     // [T,Z,Y,X] raw feats (relu here)
    const float4* __restrict__ rec,      // [N_RAYS*2] sorted records
    float4*       __restrict__ loss4)    // [N_RAYS]
{
    const int wid  = (int)((blockIdx.x * blockDim.x + threadIdx.x) >> 6);
    const int lane = (int)(threadIdx.x & 63);
    if (wid >= N_RAYS) return;

    const float4 r0 = rec[2 * wid + 0];   // wave-uniform address -> one line
    const float4 r1 = rec[2 * wid + 1];
    const float ox = r0.x, oy = r0.y, oz = r0.z;
    const int   pack = __float_as_int(r0.w);
    const int   ti = pack >> 10;
    const int   n_active = pack & 1023;
    const float ux = r1.x, uy = r1.y, uz = r1.z, gt_vox = r1.w;

    const float* gbase = grid + (size_t)ti * (size_t)(Z_DIM * Y_DIM * X_DIM);
    const int iters = (n_active + 63) >> 6;

    float lane_acc = 0.0f;   // this lane's weighted-t contributions
    float ecarry   = 1.0f;   // exp(-sum tau of previous chunks), wave-uniform

    for (int j = 0; j < iters; ++j) {
        const int step = (j << 6) + lane;
        const float tt = (float)step + 0.5f;
        const int ix = (int)floorf(fmaf(ux, tt, ox));
        const int iy = (int)floorf(fmaf(uy, tt, oy));
        const int iz = (int)floorf(fmaf(uz, tt, oz));
        const bool inb = (ix >= 0) & (ix < X_DIM) & (iy >= 0) & (iy < Y_DIM) &
                         (iz >= 0) & (iz < Z_DIM);
        float tau = 0.0f;
        if ((step < n_active) && inb) {
            tau = fmaxf(gbase[((size_t)iz * Y_DIM + (size_t)iy) * X_DIM + (size_t)ix], 0.0f);
        }

        // Inclusive prefix sum of tau across lanes (steps are lane-ordered).
        float scan = tau;
#pragma unroll
        for (int d = 1; d < 64; d <<= 1) {
            const float up = __shfl_up(scan, d, 64);
            if (lane >= d) scan += up;
        }

        // weight = e^{-(scan-tau)} - e^{-scan}; exactly 0 when tau==0.
        const float e_scan = expf(-scan);
        lane_acc += ecarry * (expf(tau - scan) - e_scan) * tt;

        ecarry *= __shfl(e_scan, 63, 64);   // e^{-chunk total}, wave-uniform
        if (ecarry < 1e-7f) break;
    }

#pragma unroll
    for (int d = 32; d >= 1; d >>= 1) lane_acc += __shfl_xor(lane_acc, d, 64);

    if (lane == 0) {
        const float pred_m = lane_acc * VOXEL_F;
        const float gt_m   = gt_vox * VOXEL_F;
        const float diff = gt_m - pred_m;
        const float ad   = fabsf(diff);
        float4 v;
        v.x = ad;
        v.y = 0.5f * diff * diff;
        v.z = ad / fmaxf(gt_m, 1e-6f);
        v.w = 1.0f;   // valid: gt >= 0 always (norm)
        loss4[wid] = v;
    }
}

__global__ __launch_bounds__(1024) void finalize_kernel(
    const float4* __restrict__ loss4, float* __restrict__ out)
{
    const int tid  = (int)threadIdx.x;
    const int lane = tid & 63;
    const int wv   = tid >> 6;
    float a = 0.0f, b = 0.0f, c = 0.0f, n = 0.0f;
    for (int i = tid; i < N_RAYS; i += 1024) {
        const float4 v = loss4[i];
        a += v.x; b += v.y; c += v.z; n += v.w;
    }
#pragma unroll
    for (int d = 32; d >= 1; d >>= 1) {
        a += __shfl_xor(a, d, 64);
        b += __shfl_xor(b, d, 64);
        c += __shfl_xor(c, d, 64);
        n += __shfl_xor(n, d, 64);
    }
    __shared__ float red[16][4];
    if (lane == 0) { red[wv][0] = a; red[wv][1] = b; red[wv][2] = c; red[wv][3] = n; }
    __syncthreads();
    if (wv == 0 && lane < 16) {
        a = red[lane][0]; b = red[lane][1]; c = red[lane][2]; n = red[lane][3];
#pragma unroll
        for (int d = 8; d >= 1; d >>= 1) {
            a += __shfl_xor(a, d, 64);
            b += __shfl_xor(b, d, 64);
            c += __shfl_xor(c, d, 64);
            n += __shfl_xor(n, d, 64);
        }
        if (lane == 0) {
            const float cnt = fmaxf(n, 1.0f);
            out[0] = a / cnt;
            out[1] = b / cnt;
            out[2] = c / cnt;
        }
    }
}

extern "C" void kernel_launch(void* const* d_in, const int* in_sizes, int n_in,
                              void* d_out, int out_size, void* d_ws, size_t ws_size,
                              hipStream_t stream) {
    const float* grid    = (const float*)d_in[0];   // (1,5,32,512,512) fp32
    const float* origin  = (const float*)d_in[1];   // (1,5,3) fp32
    const float* points  = (const float*)d_in[2];   // (1,10000,3) fp32
    const int*   tindex  = (const int*)d_in[3];     // (1,10000) int32
    float*  out   = (float*)d_out;
    float*  ws    = (float*)d_ws;
    float4* loss4 = (float4*)ws;
    float4* rec   = (float4*)(ws + REC_OFF);

    prep_kernel<<<1, 1024, 0, stream>>>(origin, points, tindex, rec);

    const int waves_per_block = 256 / 64;                                 // 4 rays/block
    const int blocks = (N_RAYS + waves_per_block - 1) / waves_per_block;  // 2500
    render_rays_kernel<<<blocks, 256, 0, stream>>>(grid, rec, loss4);

    finalize_kernel<<<1, 1024, 0, stream>>>(loss4, out);
}

// Round 6
// 209.666 us; speedup vs baseline: 1.4576x; 1.1340x over previous
//
#include <hip/hip_runtime.h>
#include <math.h>

#define T_DIM 5
#define Z_DIM 32
#define Y_DIM 512
#define X_DIM 512
#define N_RAYS 10000
#define N_STEPS 768
#define VOXEL_F 0.2f

// ws layout (floats): [0, 4*N_RAYS) per-ray float4 {|d|, .5d^2, absrel, 1.0}

// One wave per ray (natural order -- active working set is ~8 MB, L3-resident,
// so tindex-sorting buys nothing; measured R3 vs R5). Iteration j: lane L
// handles step 64j+L -> wave gather reads 64 consecutive voxels along the ray.
// Early-out when transmittance < 1e-7 (residual weight < 1e-7*768*0.2 m =
// 1.5e-4 m << 4.28 threshold). Loss: non-atomic coalesced float4 store
// (contended device atomics cost ~70-90 us here -- measured R4 vs R5).
__global__ __launch_bounds__(256) void render_rays_kernel(
    const float* __restrict__ grid,     // [T,Z,Y,X] raw feats (relu here)
    const float* __restrict__ origin,   // [T,3] meters
    const float* __restrict__ points,   // [N_RAYS,3] meters
    const int*   __restrict__ tindex,   // [N_RAYS]
    float4*      __restrict__ loss4)    // [N_RAYS]
{
    const int wid  = (int)((blockIdx.x * blockDim.x + threadIdx.x) >> 6);
    const int lane = (int)(threadIdx.x & 63);
    if (wid >= N_RAYS) return;
    const int ray = wid;

    const int ti = tindex[ray];
    const float ox = (origin[ti * 3 + 0] + 51.2f) * 5.0f;
    const float oy = (origin[ti * 3 + 1] + 51.2f) * 5.0f;
    const float oz = (origin[ti * 3 + 2] + 3.2f) * 5.0f;
    const float px = (points[ray * 3 + 0] + 51.2f) * 5.0f;
    const float py = (points[ray * 3 + 1] + 51.2f) * 5.0f;
    const float pz = (points[ray * 3 + 2] + 3.2f) * 5.0f;

    const float dx = px - ox, dy = py - oy, dz = pz - oz;
    const float gt_vox = sqrtf(dx * dx + dy * dy + dz * dz);
    const float inv = 1.0f / fmaxf(gt_vox, 1e-6f);
    const float ux = dx * inv, uy = dy * inv, uz = dz * inv;

    // Analytic exit t from box [0,X)x[0,Y)x[0,Z); origin is inside the box.
    // IEEE inf handles /0; fmaxf/fminf discard NaN (0/0). Per-step inb check
    // below still guards all edge cases exactly.
    float thi = 1e30f;
    thi = fminf(thi, fmaxf((0.0f - ox) / ux, ((float)X_DIM - ox) / ux));
    thi = fminf(thi, fmaxf((0.0f - oy) / uy, ((float)Y_DIM - oy) / uy));
    thi = fminf(thi, fmaxf((0.0f - oz) / uz, ((float)Z_DIM - oz) / uz));
    int n_active = (int)ceilf(fminf(thi, 769.0f) - 0.5f);  // steps k with k+0.5 < thi
    n_active = min(N_STEPS, max(0, n_active));
    const int iters = (n_active + 63) >> 6;

    const float* gbase = grid + (size_t)ti * (size_t)(Z_DIM * Y_DIM * X_DIM);

    float lane_acc = 0.0f;   // this lane's weighted-t contributions
    float ecarry   = 1.0f;   // exp(-sum tau of previous chunks), wave-uniform

    for (int j = 0; j < iters; ++j) {
        const int step = (j << 6) + lane;
        const float tt = (float)step + 0.5f;
        const int ix = (int)floorf(fmaf(ux, tt, ox));
        const int iy = (int)floorf(fmaf(uy, tt, oy));
        const int iz = (int)floorf(fmaf(uz, tt, oz));
        const bool inb = (ix >= 0) & (ix < X_DIM) & (iy >= 0) & (iy < Y_DIM) &
                         (iz >= 0) & (iz < Z_DIM);
        float tau = 0.0f;
        if ((step < n_active) && inb) {
            tau = fmaxf(gbase[((size_t)iz * Y_DIM + (size_t)iy) * X_DIM + (size_t)ix], 0.0f);
        }

        // Inclusive prefix sum of tau across lanes (steps are lane-ordered).
        float scan = tau;
#pragma unroll
        for (int d = 1; d < 64; d <<= 1) {
            const float up = __shfl_up(scan, d, 64);
            if (lane >= d) scan += up;
        }

        // weight = e^{-(scan-tau)} - e^{-scan}; exactly 0 when tau==0.
        const float e_scan = expf(-scan);
        lane_acc += ecarry * (expf(tau - scan) - e_scan) * tt;

        ecarry *= __shfl(e_scan, 63, 64);   // e^{-chunk total}, wave-uniform
        if (ecarry < 1e-7f) break;
    }

#pragma unroll
    for (int d = 32; d >= 1; d >>= 1) lane_acc += __shfl_xor(lane_acc, d, 64);

    if (lane == 0) {
        const float pred_m = lane_acc * VOXEL_F;
        const float gt_m   = gt_vox * VOXEL_F;
        const float diff = gt_m - pred_m;
        const float ad   = fabsf(diff);
        float4 v;
        v.x = ad;
        v.y = 0.5f * diff * diff;
        v.z = ad / fmaxf(gt_m, 1e-6f);
        v.w = 1.0f;   // valid: gt >= 0 always (norm)
        loss4[wid] = v;
    }
}

__global__ __launch_bounds__(1024) void finalize_kernel(
    const float4* __restrict__ loss4, float* __restrict__ out)
{
    const int tid  = (int)threadIdx.x;
    const int lane = tid & 63;
    const int wv   = tid >> 6;
    float a = 0.0f, b = 0.0f, c = 0.0f, n = 0.0f;
    for (int i = tid; i < N_RAYS; i += 1024) {
        const float4 v = loss4[i];
        a += v.x; b += v.y; c += v.z; n += v.w;
    }
#pragma unroll
    for (int d = 32; d >= 1; d >>= 1) {
        a += __shfl_xor(a, d, 64);
        b += __shfl_xor(b, d, 64);
        c += __shfl_xor(c, d, 64);
        n += __shfl_xor(n, d, 64);
    }
    __shared__ float red[16][4];
    if (lane == 0) { red[wv][0] = a; red[wv][1] = b; red[wv][2] = c; red[wv][3] = n; }
    __syncthreads();
    if (wv == 0 && lane < 16) {
        a = red[lane][0]; b = red[lane][1]; c = red[lane][2]; n = red[lane][3];
#pragma unroll
        for (int d = 8; d >= 1; d >>= 1) {
            a += __shfl_xor(a, d, 64);
            b += __shfl_xor(b, d, 64);
            c += __shfl_xor(c, d, 64);
            n += __shfl_xor(n, d, 64);
        }
        if (lane == 0) {
            const float cnt = fmaxf(n, 1.0f);
            out[0] = a / cnt;
            out[1] = b / cnt;
            out[2] = c / cnt;
        }
    }
}

extern "C" void kernel_launch(void* const* d_in, const int* in_sizes, int n_in,
                              void* d_out, int out_size, void* d_ws, size_t ws_size,
                              hipStream_t stream) {
    const float* grid    = (const float*)d_in[0];   // (1,5,32,512,512) fp32
    const float* origin  = (const float*)d_in[1];   // (1,5,3) fp32
    const float* points  = (const float*)d_in[2];   // (1,10000,3) fp32
    const int*   tindex  = (const int*)d_in[3];     // (1,10000) int32
    float*  out   = (float*)d_out;
    float4* loss4 = (float4*)d_ws;

    const int waves_per_block = 256 / 64;                                 // 4 rays/block
    const int blocks = (N_RAYS + waves_per_block - 1) / waves_per_block;  // 2500
    render_rays_kernel<<<blocks, 256, 0, stream>>>(grid, origin, points, tindex, loss4);

    finalize_kernel<<<1, 1024, 0, stream>>>(loss4, out);
}

// Round 7
// 206.079 us; speedup vs baseline: 1.4830x; 1.0174x over previous
//
#include <hip/hip_runtime.h>
#include <math.h>

#define T_DIM 5
#define Z_DIM 32
#define Y_DIM 512
#define X_DIM 512
#define N_RAYS 10000
#define N_STEPS 768
#define VOXEL_F 0.2f
#define RAYS_PER_BLOCK 16                      // 1024 thr = 16 waves = 16 rays
#define N_BLOCKS (N_RAYS / RAYS_PER_BLOCK)     // 625, exact

// ws layout: float4 partials[N_BLOCKS] (10 KB) at offset 0.

// One wave per ray; 16 rays per 1024-thread block, block-reduced to one
// float4 partial. Lane L of iteration j handles step 64j+L. Every in-bounds
// 64-step chunk has sum(tau) ~ 25 (tau = relu(N(0,1))), so transmittance
// dies in chunk 1 and the early-out (trans < 1e-7, residual weight
// < 1e-7*768*0.2 m = 1.5e-4 m << 4.28 threshold) fires after one iteration.
// Loss path is non-atomic (contended device atomics cost ~70-90 us here --
// measured R4 vs R5). Origin table (15 floats) is loaded unconditionally in
// parallel with tindex/points and selected after readfirstlane(ti), so the
// per-wave dependent-load chain is 2 deep, not 3. The per-step in-box check
// alone is exact (box is convex; past exit all steps contribute 0), so
// n_active only bounds the loop and its divides stay off the critical path.
__global__ __launch_bounds__(1024) void render_rays_kernel(
    const float* __restrict__ grid,     // [T,Z,Y,X] raw feats (relu here)
    const float* __restrict__ origin,   // [T,3] meters
    const float* __restrict__ points,   // [N_RAYS,3] meters
    const int*   __restrict__ tindex,   // [N_RAYS]
    float4*      __restrict__ partials) // [N_BLOCKS]
{
    const int wv   = (int)(threadIdx.x >> 6);            // 0..15
    const int lane = (int)(threadIdx.x & 63);
    const int ray  = (int)blockIdx.x * RAYS_PER_BLOCK + wv;   // < N_RAYS always

    // Independent loads, all issued up front.
    const int ti = __builtin_amdgcn_readfirstlane(tindex[ray]);
    const float px = (points[ray * 3 + 0] + 51.2f) * 5.0f;
    const float py = (points[ray * 3 + 1] + 51.2f) * 5.0f;
    const float pz = (points[ray * 3 + 2] + 3.2f) * 5.0f;
    const float o0  = origin[0],  o1  = origin[1],  o2  = origin[2];
    const float o3  = origin[3],  o4  = origin[4],  o5  = origin[5];
    const float o6  = origin[6],  o7  = origin[7],  o8  = origin[8];
    const float o9  = origin[9],  o10 = origin[10], o11 = origin[11];
    const float o12 = origin[12], o13 = origin[13], o14 = origin[14];

    float oxm = o0, oym = o1, ozm = o2;          // ti-selected origin (scalar selects)
    if (ti == 1) { oxm = o3;  oym = o4;  ozm = o5;  }
    if (ti == 2) { oxm = o6;  oym = o7;  ozm = o8;  }
    if (ti == 3) { oxm = o9;  oym = o10; ozm = o11; }
    if (ti == 4) { oxm = o12; oym = o13; ozm = o14; }
    const float ox = (oxm + 51.2f) * 5.0f;
    const float oy = (oym + 51.2f) * 5.0f;
    const float oz = (ozm + 3.2f) * 5.0f;

    const float dx = px - ox, dy = py - oy, dz = pz - oz;
    const float gt_vox = sqrtf(dx * dx + dy * dy + dz * dz);
    const float inv = 1.0f / fmaxf(gt_vox, 1e-6f);
    const float ux = dx * inv, uy = dy * inv, uz = dz * inv;

    const float* gbase = grid + (size_t)ti * (size_t)(Z_DIM * Y_DIM * X_DIM);

    // Loop bound only (correctness rests on the per-step inb check; the box
    // is convex so steps past exit contribute exactly 0). Origin is inside.
    float thi = 1e30f;
    thi = fminf(thi, fmaxf((0.0f - ox) / ux, ((float)X_DIM - ox) / ux));
    thi = fminf(thi, fmaxf((0.0f - oy) / uy, ((float)Y_DIM - oy) / uy));
    thi = fminf(thi, fmaxf((0.0f - oz) / uz, ((float)Z_DIM - oz) / uz));
    int n_active = (int)ceilf(fminf(thi, 769.0f) - 0.5f);
    n_active = min(N_STEPS, max(1, n_active));
    const int iters = (n_active + 63) >> 6;

    float lane_acc = 0.0f;   // this lane's weighted-t contributions
    float ecarry   = 1.0f;   // exp(-sum tau of previous chunks), wave-uniform

    for (int j = 0; j < iters; ++j) {
        const int step = (j << 6) + lane;
        const float tt = (float)step + 0.5f;
        const int ix = (int)floorf(fmaf(ux, tt, ox));
        const int iy = (int)floorf(fmaf(uy, tt, oy));
        const int iz = (int)floorf(fmaf(uz, tt, oz));
        const bool inb = (ix >= 0) & (ix < X_DIM) & (iy >= 0) & (iy < Y_DIM) &
                         (iz >= 0) & (iz < Z_DIM);
        float tau = 0.0f;
        if (inb) {
            tau = fmaxf(gbase[((size_t)iz * Y_DIM + (size_t)iy) * X_DIM + (size_t)ix], 0.0f);
        }

        // Inclusive prefix sum of tau across lanes (steps are lane-ordered).
        float scan = tau;
#pragma unroll
        for (int d = 1; d < 64; d <<= 1) {
            const float up = __shfl_up(scan, d, 64);
            if (lane >= d) scan += up;
        }

        // weight = e^{-(scan-tau)} - e^{-scan}; exactly 0 when tau==0.
        const float e_scan = expf(-scan);
        lane_acc += ecarry * (expf(tau - scan) - e_scan) * tt;

        ecarry *= __shfl(e_scan, 63, 64);   // e^{-chunk total}, wave-uniform
        if (ecarry < 1e-7f) break;
    }

#pragma unroll
    for (int d = 32; d >= 1; d >>= 1) lane_acc += __shfl_xor(lane_acc, d, 64);

    // Per-block reduction of the 16 per-ray loss tuples.
    __shared__ float4 slots[RAYS_PER_BLOCK];
    if (lane == 0) {
        const float pred_m = lane_acc * VOXEL_F;
        const float gt_m   = gt_vox * VOXEL_F;
        const float diff = gt_m - pred_m;
        const float ad   = fabsf(diff);
        float4 v;
        v.x = ad;
        v.y = 0.5f * diff * diff;
        v.z = ad / fmaxf(gt_m, 1e-6f);
        v.w = 0.0f;
        slots[wv] = v;
    }
    __syncthreads();
    if (wv == 0) {
        float a = 0.0f, b = 0.0f, c = 0.0f;
        if (lane < RAYS_PER_BLOCK) {
            const float4 v = slots[lane];
            a = v.x; b = v.y; c = v.z;
        }
#pragma unroll
        for (int d = 8; d >= 1; d >>= 1) {
            a += __shfl_xor(a, d, 64);
            b += __shfl_xor(b, d, 64);
            c += __shfl_xor(c, d, 64);
        }
        if (lane == 0) {
            float4 p; p.x = a; p.y = b; p.z = c; p.w = 0.0f;
            partials[blockIdx.x] = p;
        }
    }
}

__global__ __launch_bounds__(256) void finalize_kernel(
    const float4* __restrict__ partials, float* __restrict__ out)
{
    const int tid  = (int)threadIdx.x;
    const int lane = tid & 63;
    const int wv   = tid >> 6;
    float a = 0.0f, b = 0.0f, c = 0.0f;
    for (int i = tid; i < N_BLOCKS; i += 256) {
        const float4 v = partials[i];
        a += v.x; b += v.y; c += v.z;
    }
#pragma unroll
    for (int d = 32; d >= 1; d >>= 1) {
        a += __shfl_xor(a, d, 64);
        b += __shfl_xor(b, d, 64);
        c += __shfl_xor(c, d, 64);
    }
    __shared__ float red[4][3];
    if (lane == 0) { red[wv][0] = a; red[wv][1] = b; red[wv][2] = c; }
    __syncthreads();
    if (wv == 0 && lane < 4) {
        a = red[lane][0]; b = red[lane][1]; c = red[lane][2];
#pragma unroll
        for (int d = 2; d >= 1; d >>= 1) {
            a += __shfl_xor(a, d, 64);
            b += __shfl_xor(b, d, 64);
            c += __shfl_xor(c, d, 64);
        }
        if (lane == 0) {
            const float cnt = (float)N_RAYS;   // gt = norm >= 0 always
            out[0] = a / cnt;
            out[1] = b / cnt;
            out[2] = c / cnt;
        }
    }
}

extern "C" void kernel_launch(void* const* d_in, const int* in_sizes, int n_in,
                              void* d_out, int out_size, void* d_ws, size_t ws_size,
                              hipStream_t stream) {
    const float* grid    = (const float*)d_in[0];   // (1,5,32,512,512) fp32
    const float* origin  = (const float*)d_in[1];   // (1,5,3) fp32
    const float* points  = (const float*)d_in[2];   // (1,10000,3) fp32
    const int*   tindex  = (const int*)d_in[3];     // (1,10000) int32
    float*  out      = (float*)d_out;
    float4* partials = (float4*)d_ws;

    render_rays_kernel<<<N_BLOCKS, 1024, 0, stream>>>(grid, origin, points, tindex, partials);
    finalize_kernel<<<1, 256, 0, stream>>>(partials, out);
}